// Round 3
// baseline (744.053 us; speedup 1.0000x reference)
//
#include <hip/hip_runtime.h>
#include <hip/hip_bf16.h>
#include <cstdint>
#include <cstddef>

#define N_NODES 32768
#define N_EDGES 262144
#define BGRAPH  32
#define NPG     1024
#define KSEL    820
#define NEG     0.2f

// ---------------------------------------------------------------------------
// GEMM: xl = x@Wl + bl ; xr = x@Wr + br   (fp32 VALU, unchanged this round)
// ---------------------------------------------------------------------------
#define BM 128
#define BN 128
#define BK 16

__global__ __launch_bounds__(256) void gemm_xlxr(
    const float* __restrict__ x,
    const float* __restrict__ Wl, const float* __restrict__ bl,
    const float* __restrict__ Wr, const float* __restrict__ br,
    float* __restrict__ xl, float* __restrict__ xr)
{
    __shared__ float As[BK][BM];
    __shared__ float Bs[BK][BN];

    const int bm = blockIdx.x;      // 0..255
    const int bn = blockIdx.y;      // 0..7
    const float* W; const float* bias; float* out; int colbase;
    if (bn < 4) { W = Wl; bias = bl; out = xl; colbase = bn * 128; }
    else        { W = Wr; bias = br; out = xr; colbase = (bn - 4) * 128; }

    const int tid = threadIdx.x;
    const int tm = tid >> 4;        // 0..15
    const int tn = tid & 15;        // 0..15

    float acc[8][8];
#pragma unroll
    for (int i = 0; i < 8; ++i)
#pragma unroll
        for (int j = 0; j < 8; ++j) acc[i][j] = 0.f;

    for (int k0 = 0; k0 < 256; k0 += BK) {
        __syncthreads();
#pragma unroll
        for (int p = 0; p < 2; ++p) {
            int id  = tid + p * 256;
            int row = id >> 2;
            int kc  = (id & 3) << 2;
            float4 v = *(const float4*)&x[(size_t)(bm * BM + row) * 256 + k0 + kc];
            As[kc + 0][row] = v.x; As[kc + 1][row] = v.y;
            As[kc + 2][row] = v.z; As[kc + 3][row] = v.w;
        }
#pragma unroll
        for (int p = 0; p < 2; ++p) {
            int id = tid + p * 256;
            int kk = id >> 5;
            int nf = (id & 31) << 2;
            float4 v = *(const float4*)&W[(size_t)(k0 + kk) * 512 + colbase + nf];
            *(float4*)&Bs[kk][nf] = v;
        }
        __syncthreads();
#pragma unroll
        for (int kk = 0; kk < BK; ++kk) {
            float a[8], b[8];
            *(float4*)&a[0] = *(const float4*)&As[kk][tm * 8];
            *(float4*)&a[4] = *(const float4*)&As[kk][tm * 8 + 4];
            *(float4*)&b[0] = *(const float4*)&Bs[kk][tn * 8];
            *(float4*)&b[4] = *(const float4*)&Bs[kk][tn * 8 + 4];
#pragma unroll
            for (int i = 0; i < 8; ++i)
#pragma unroll
                for (int j = 0; j < 8; ++j) acc[i][j] += a[i] * b[j];
        }
    }

    float bv[8];
    *(float4*)&bv[0] = *(const float4*)&bias[colbase + tn * 8];
    *(float4*)&bv[4] = *(const float4*)&bias[colbase + tn * 8 + 4];
#pragma unroll
    for (int i = 0; i < 8; ++i) {
        int row = bm * BM + tm * 8 + i;
        float4 o0 = make_float4(acc[i][0] + bv[0], acc[i][1] + bv[1],
                                acc[i][2] + bv[2], acc[i][3] + bv[3]);
        float4 o1 = make_float4(acc[i][4] + bv[4], acc[i][5] + bv[5],
                                acc[i][6] + bv[6], acc[i][7] + bv[7]);
        *(float4*)&out[(size_t)row * 512 + colbase + tn * 8]     = o0;
        *(float4*)&out[(size_t)row * 512 + colbase + tn * 8 + 4] = o1;
    }
}

// ---------------------------------------------------------------------------
// Counting sort of edges by dst
// ---------------------------------------------------------------------------
__global__ void k_hist(const int* __restrict__ ei, int* __restrict__ counts)
{
    int e = blockIdx.x * 256 + threadIdx.x;
    if (e < N_EDGES) atomicAdd(&counts[ei[N_EDGES + e]], 1);
}

__global__ __launch_bounds__(1024) void k_scan(
    const int* __restrict__ counts, int* __restrict__ offsets, int* __restrict__ cursors)
{
    __shared__ int part[1024];
    const int tid = threadIdx.x;
    const int base = tid * 32;
    int loc[32];
    int s = 0;
#pragma unroll
    for (int i = 0; i < 32; ++i) { loc[i] = s; s += counts[base + i]; }
    part[tid] = s;
    __syncthreads();
    const int own = s;
    for (int off = 1; off < 1024; off <<= 1) {
        int v = (tid >= off) ? part[tid - off] : 0;
        __syncthreads();
        part[tid] += v;
        __syncthreads();
    }
    const int pre = part[tid] - own;   // exclusive prefix of chunk
#pragma unroll
    for (int i = 0; i < 32; ++i) {
        int o = pre + loc[i];
        offsets[base + i] = o;
        cursors[base + i] = o;
    }
}

__global__ void k_scatter(const int* __restrict__ ei, int* __restrict__ cursors,
                          int* __restrict__ sorted_src, int* __restrict__ sorted_dst,
                          int* __restrict__ sorted_eid)
{
    int e = blockIdx.x * 256 + threadIdx.x;
    if (e >= N_EDGES) return;
    int d = ei[N_EDGES + e];
    int pos = atomicAdd(&cursors[d], 1);
    sorted_src[pos] = ei[e];
    sorted_dst[pos] = d;
    sorted_eid[pos] = e;
}

// ---------------------------------------------------------------------------
// k_alpha: per-edge logits, edge-parallel, no cross-edge dependencies.
// 256 threads; lane owns 2 consecutive channels (c0 = 2*tid); 32-lane group
// owns one head. We fragment = 64 VGPRs (float2 x 32). ea row / src / dst
// are block-uniform -> scalar loads. 2-edge unroll for ILP.
// ---------------------------------------------------------------------------
#define EPB 32

__global__ __launch_bounds__(256, 4) void k_alpha(
    const float* __restrict__ xl, const float* __restrict__ xr,
    const float* __restrict__ ea, const float* __restrict__ We,
    const float* __restrict__ att,
    const int* __restrict__ sorted_src, const int* __restrict__ sorted_dst,
    const int* __restrict__ sorted_eid,
    float* __restrict__ logits)
{
    const int tid = threadIdx.x;
    const int c0 = tid * 2;
    const int head = tid >> 5;
    const int lead = ((tid & 31) == 0);

    float2 wr[32];
#pragma unroll
    for (int k = 0; k < 32; ++k)
        wr[k] = *(const float2*)&We[k * 512 + c0];
    const float2 attv = *(const float2*)&att[c0];

    const int p0 = blockIdx.x * EPB;
    for (int j = 0; j < EPB; j += 2) {
        const int pA = p0 + j, pB = p0 + j + 1;
        const int sA = sorted_src[pA], sB = sorted_src[pB];
        const int dA = sorted_dst[pA], dB = sorted_dst[pB];
        const int eA = sorted_eid[pA], eB = sorted_eid[pB];
        const float2 xlA = *(const float2*)&xl[(size_t)sA * 512 + c0];
        const float2 xrA = *(const float2*)&xr[(size_t)dA * 512 + c0];
        const float2 xlB = *(const float2*)&xl[(size_t)sB * 512 + c0];
        const float2 xrB = *(const float2*)&xr[(size_t)dB * 512 + c0];
        const float* eaA = &ea[(size_t)eA * 32];
        const float* eaB = &ea[(size_t)eB * 32];

        float a0 = 0.f, a1 = 0.f, b0 = 0.f, b1 = 0.f;
#pragma unroll
        for (int k = 0; k < 32; ++k) {
            const float evA = eaA[k];
            const float evB = eaB[k];
            a0 += evA * wr[k].x; a1 += evA * wr[k].y;
            b0 += evB * wr[k].x; b1 += evB * wr[k].y;
        }
        float tA0 = xlA.x + xrA.x + a0; tA0 = tA0 > 0.f ? tA0 : NEG * tA0;
        float tA1 = xlA.y + xrA.y + a1; tA1 = tA1 > 0.f ? tA1 : NEG * tA1;
        float tB0 = xlB.x + xrB.x + b0; tB0 = tB0 > 0.f ? tB0 : NEG * tB0;
        float tB1 = xlB.y + xrB.y + b1; tB1 = tB1 > 0.f ? tB1 : NEG * tB1;

        float lA = tA0 * attv.x + tA1 * attv.y;
        float lB = tB0 * attv.x + tB1 * attv.y;
#pragma unroll
        for (int o = 1; o < 32; o <<= 1) {
            lA += __shfl_xor(lA, o);
            lB += __shfl_xor(lB, o);
        }
        if (lead) {
            logits[(size_t)pA * 8 + head] = lA;
            logits[(size_t)pB * 8 + head] = lB;
        }
    }
}

// ---------------------------------------------------------------------------
// k_agg: per-dst two-pass softmax + weighted xl[src] gather-sum, then
// h = relu(out+bias), score = tanh(h.pw/||pw||). Lane owns 2 channels and
// tracks only its own head's max/denom (identical within the 32-lane group,
// so no reduces in the loop). Tiny VGPR -> high occupancy hides gather
// latency.
// ---------------------------------------------------------------------------
#define AGG_DPB 8

__global__ __launch_bounds__(256, 8) void k_agg(
    const float* __restrict__ xl, const float* __restrict__ logits,
    const int* __restrict__ sorted_src,
    const int* __restrict__ offsets, const int* __restrict__ counts,
    const float* __restrict__ bias, const float* __restrict__ pw,
    float* __restrict__ h, float* __restrict__ score)
{
    __shared__ float red_s[4];

    const int tid = threadIdx.x;
    const int wv  = tid >> 6;
    const int l   = tid & 63;
    const int c0  = tid * 2;
    const int head = tid >> 5;

    const float2 bv  = *(const float2*)&bias[c0];
    const float2 pwv = *(const float2*)&pw[c0];

    float nrm = pwv.x * pwv.x + pwv.y * pwv.y;
#pragma unroll
    for (int o = 1; o < 64; o <<= 1) nrm += __shfl_xor(nrm, o);
    if (l == 0) red_s[wv] = nrm;
    __syncthreads();
    const float inv_nrm = 1.0f / sqrtf(red_s[0] + red_s[1] + red_s[2] + red_s[3]);

    for (int dd = 0; dd < AGG_DPB; ++dd) {
        const int d   = blockIdx.x * AGG_DPB + dd;
        const int off = offsets[d];
        const int deg = counts[d];

        float m = -INFINITY;
        for (int j = 0; j < deg; ++j)
            m = fmaxf(m, logits[(size_t)(off + j) * 8 + head]);

        float den = 0.f, a0 = 0.f, a1 = 0.f;
        for (int j = 0; j < deg; ++j) {
            const float lg = logits[(size_t)(off + j) * 8 + head];
            const int   s  = sorted_src[off + j];
            const float2 xl2 = *(const float2*)&xl[(size_t)s * 512 + c0];
            const float pe = __expf(lg - m);
            den += pe;
            a0 += pe * xl2.x;
            a1 += pe * xl2.y;
        }

        const float r = den > 0.f ? 1.0f / den : 0.f;
        const float h0 = fmaxf(a0 * r + bv.x, 0.f);
        const float h1 = fmaxf(a1 * r + bv.y, 0.f);
        *(float2*)&h[(size_t)d * 512 + c0] = make_float2(h0, h1);

        float ps = h0 * pwv.x + h1 * pwv.y;
#pragma unroll
        for (int o = 1; o < 64; o <<= 1) ps += __shfl_xor(ps, o);
        __syncthreads();
        if (l == 0) red_s[wv] = ps;
        __syncthreads();
        if (tid == 0)
            score[d] = tanhf((red_s[0] + red_s[1] + red_s[2] + red_s[3]) * inv_nrm);
    }
}

// ---------------------------------------------------------------------------
// Per-graph top-K via bitonic sort of packed keys (score desc, idx asc)
// ---------------------------------------------------------------------------
__global__ __launch_bounds__(256) void k_topk(const float* __restrict__ score,
                                              int* __restrict__ sel_idx,
                                              float* __restrict__ sel_val)
{
    __shared__ unsigned long long key[1024];
    const int g = blockIdx.x, tid = threadIdx.x;
    for (int i = tid; i < 1024; i += 256) {
        float s = score[g * 1024 + i];
        unsigned u = __float_as_uint(s);
        u = (u & 0x80000000u) ? ~u : (u | 0x80000000u);   // orderable, ascending
        key[i] = ((unsigned long long)(~u) << 32) | (unsigned)i;  // asc key == desc score
    }
    __syncthreads();
    for (int k = 2; k <= 1024; k <<= 1) {
        for (int j = k >> 1; j > 0; j >>= 1) {
            for (int i = tid; i < 1024; i += 256) {
                int ixj = i ^ j;
                if (ixj > i) {
                    bool up = ((i & k) == 0);
                    unsigned long long a = key[i], b = key[ixj];
                    if ((a > b) == up) { key[i] = b; key[ixj] = a; }
                }
            }
            __syncthreads();
        }
    }
    for (int kk = tid; kk < KSEL; kk += 256) {
        int idx = (int)(key[kk] & 0xFFFFFFFFu);
        sel_idx[g * KSEL + kk] = idx;
        sel_val[g * KSEL + kk] = score[g * 1024 + idx];
    }
}

// ---------------------------------------------------------------------------
// Pool: gmp = max_k(h[idx_k]*val_k), gap = mean_k(...) — k-sliced + merge
// ---------------------------------------------------------------------------
#define KSLICE 103

__global__ __launch_bounds__(256) void k_pool_part(
    const float* __restrict__ h, const int* __restrict__ sel_idx,
    const float* __restrict__ sel_val, float* __restrict__ part)
{
    const int g = blockIdx.x >> 3, sl = blockIdx.x & 7;
    const int kbeg = sl * KSLICE;
    const int kend = min(KSEL, kbeg + KSLICE);
    const int n = kend - kbeg;
    __shared__ float vs[KSLICE];
    __shared__ int   is_[KSLICE];
    const int tid = threadIdx.x;
    if (tid < n) {
        vs[tid]  = sel_val[g * KSEL + kbeg + tid];
        is_[tid] = sel_idx[g * KSEL + kbeg + tid];
    }
    __syncthreads();
    const int c0 = tid, c1 = tid + 256;
    float mx0 = -INFINITY, mx1 = -INFINITY, s0 = 0.f, s1 = 0.f;
    for (int kk = 0; kk < n; ++kk) {
        const float* hp = h + ((size_t)(g * 1024 + is_[kk])) * 512;
        const float v = vs[kk];
        float f0 = hp[c0] * v, f1 = hp[c1] * v;
        mx0 = fmaxf(mx0, f0); s0 += f0;
        mx1 = fmaxf(mx1, f1); s1 += f1;
    }
    const size_t base = ((size_t)blockIdx.x * 2) * 512;
    part[base + c0] = mx0;        part[base + c1] = mx1;
    part[base + 512 + c0] = s0;   part[base + 512 + c1] = s1;
}

__global__ __launch_bounds__(256) void k_pool_merge(
    const float* __restrict__ part, float* __restrict__ out)
{
    const int g = blockIdx.x, tid = threadIdx.x;
    const int c0 = tid, c1 = tid + 256;
    float mx0 = -INFINITY, mx1 = -INFINITY, s0 = 0.f, s1 = 0.f;
    for (int sl = 0; sl < 8; ++sl) {
        const size_t base = ((size_t)(g * 8 + sl) * 2) * 512;
        mx0 = fmaxf(mx0, part[base + c0]); mx1 = fmaxf(mx1, part[base + c1]);
        s0 += part[base + 512 + c0];       s1 += part[base + 512 + c1];
    }
    out[(size_t)g * 1024 + c0] = mx0;
    out[(size_t)g * 1024 + c1] = mx1;
    out[(size_t)g * 1024 + 512 + c0] = s0 * (1.f / KSEL);
    out[(size_t)g * 1024 + 512 + c1] = s1 * (1.f / KSEL);
}

// ---------------------------------------------------------------------------
extern "C" void kernel_launch(void* const* d_in, const int* in_sizes, int n_in,
                              void* d_out, int out_size, void* d_ws, size_t ws_size,
                              hipStream_t stream)
{
    const float* x    = (const float*)d_in[0];
    const float* ea   = (const float*)d_in[1];
    const float* Wl   = (const float*)d_in[2];
    const float* bl   = (const float*)d_in[3];
    const float* Wr   = (const float*)d_in[4];
    const float* br   = (const float*)d_in[5];
    const float* We   = (const float*)d_in[6];
    const float* att  = (const float*)d_in[7];
    const float* bias = (const float*)d_in[8];
    const float* pw   = (const float*)d_in[9];
    const int*   ei   = (const int*)d_in[10];
    float* out = (float*)d_out;

    // workspace layout (floats/ints, 4B each)
    float* xl        = (float*)d_ws;                      // N*512
    float* xr        = xl + (size_t)N_NODES * 512;
    float* h         = xr + (size_t)N_NODES * 512;
    float* logits    = h + (size_t)N_NODES * 512;         // E*8
    float* sel_val   = logits + (size_t)N_EDGES * 8;      // 32*820
    float* part      = sel_val + BGRAPH * KSEL;           // 256*2*512
    float* score     = part + 256 * 2 * 512;              // 32768
    int* counts      = (int*)(score + N_NODES);
    int* offsets     = counts + N_NODES;
    int* cursors     = offsets + N_NODES;
    int* sorted_src  = cursors + N_NODES;                 // E
    int* sorted_dst  = sorted_src + N_EDGES;              // E
    int* sorted_eid  = sorted_dst + N_EDGES;              // E
    int* sel_idx     = sorted_eid + N_EDGES;              // 32*820

    hipMemsetAsync(counts, 0, (size_t)N_NODES * sizeof(int), stream);

    gemm_xlxr<<<dim3(256, 8), 256, 0, stream>>>(x, Wl, bl, Wr, br, xl, xr);
    k_hist<<<N_EDGES / 256, 256, 0, stream>>>(ei, counts);
    k_scan<<<1, 1024, 0, stream>>>(counts, offsets, cursors);
    k_scatter<<<N_EDGES / 256, 256, 0, stream>>>(ei, cursors, sorted_src, sorted_dst, sorted_eid);
    k_alpha<<<N_EDGES / EPB, 256, 0, stream>>>(xl, xr, ea, We, att,
                                               sorted_src, sorted_dst, sorted_eid, logits);
    k_agg<<<N_NODES / AGG_DPB, 256, 0, stream>>>(xl, logits, sorted_src, offsets, counts,
                                                 bias, pw, h, score);
    k_topk<<<BGRAPH, 256, 0, stream>>>(score, sel_idx, sel_val);
    k_pool_part<<<BGRAPH * 8, 256, 0, stream>>>(h, sel_idx, sel_val, part);
    k_pool_merge<<<BGRAPH, 256, 0, stream>>>(part, out);
}

// Round 5
// 679.724 us; speedup vs baseline: 1.0946x; 1.0946x over previous
//
#include <hip/hip_runtime.h>
#include <hip/hip_bf16.h>
#include <cstdint>
#include <cstddef>

#define N_NODES 32768
#define N_EDGES 262144
#define BGRAPH  32
#define NPG     1024
#define KSEL    820
#define NEG     0.2f

typedef unsigned short u16;
typedef __attribute__((ext_vector_type(4))) float f32x4;
typedef __attribute__((ext_vector_type(8))) short s16x8;

static __device__ __forceinline__ u16 f2bf(float v) {
    __hip_bfloat16 b(v);
    return *reinterpret_cast<u16*>(&b);
}
static __device__ __forceinline__ float bf2f(u16 u) {
    __hip_bfloat16 b = *reinterpret_cast<__hip_bfloat16*>(&u);
    return (float)b;
}

// ---------------------------------------------------------------------------
// Prep: split x into bf16 hi/lo (x = hi + lo + eps, eps ~ 2^-16 rel)
// ---------------------------------------------------------------------------
__global__ __launch_bounds__(256) void k_split_x(
    const float* __restrict__ x, u16* __restrict__ xhi, u16* __restrict__ xlo)
{
    const int i = blockIdx.x * 256 + threadIdx.x;      // one float4 per thread
    const float4 v = *(const float4*)&x[(size_t)i * 4];
    u16 h0 = f2bf(v.x), h1 = f2bf(v.y), h2 = f2bf(v.z), h3 = f2bf(v.w);
    u16 l0 = f2bf(v.x - bf2f(h0));
    u16 l1 = f2bf(v.y - bf2f(h1));
    u16 l2 = f2bf(v.z - bf2f(h2));
    u16 l3 = f2bf(v.w - bf2f(h3));
    *(ushort4*)&xhi[(size_t)i * 4] = make_ushort4(h0, h1, h2, h3);
    *(ushort4*)&xlo[(size_t)i * 4] = make_ushort4(l0, l1, l2, l3);
}

// ---------------------------------------------------------------------------
// Prep: packed transposed B' [1024 n][768 k'] bf16.
//   k'<256: hi(W[k']) ; 256..511: lo(W[k'-256]) ; >=512: hi(W[k'-512])
//   n<512 -> Wl, else Wr.
// ---------------------------------------------------------------------------
__global__ __launch_bounds__(256) void k_pack_bt(
    const float* __restrict__ Wl, const float* __restrict__ Wr,
    u16* __restrict__ BpT)
{
    const int kp = blockIdx.x * 256 + threadIdx.x;     // 0..767 (grid.x = 3)
    const int n  = blockIdx.y;                         // 0..1023
    if (kp >= 768) return;
    const float* W = (n < 512) ? Wl : Wr;
    const int col = n & 511;
    const int k = kp & 255;
    const float v = W[(size_t)k * 512 + col];
    const u16 h = f2bf(v);
    const u16 o = (kp >= 256 && kp < 512) ? f2bf(v - bf2f(h)) : h;
    BpT[(size_t)n * 768 + kp] = o;
}

// ---------------------------------------------------------------------------
// Split-bf16 MFMA GEMM: C[32768 x 1024] = A'[M x 768] @ B'[768 x 1024] + bias
// A' = [xhi | xhi | xlo] (handled by source select in staging).
// 128x128 tile, 256 thr (4 waves, 2x2 of 64x64), 16x16x32 bf16 MFMA.
// LDS XOR-swizzled [row][k] layout for both A and B(transposed).
// ---------------------------------------------------------------------------
__global__ __launch_bounds__(256) void gemm_mfma(
    const u16* __restrict__ xhi, const u16* __restrict__ xlo,
    const u16* __restrict__ BpT,
    const float* __restrict__ bl, const float* __restrict__ br,
    float* __restrict__ xl, float* __restrict__ xr)
{
    __shared__ u16 As[128 * 64];
    __shared__ u16 Bs[128 * 64];

    // XCD-aware swizzle: 2048 blocks, 8 XCDs -> each XCD owns one N-tile.
    const int raw = blockIdx.x;
    const int swz = (raw & 7) * 256 + (raw >> 3);
    const int mt = swz & 255, nt = swz >> 8;
    const int m0 = mt * 128, n0 = nt * 128;

    const int tid  = threadIdx.x;
    const int lane = tid & 63;
    const int wid  = tid >> 6;
    const int wr   = wid >> 1, wc = wid & 1;      // 64x64 wave tile
    const int lr   = lane & 15;                   // frag row/col
    const int lk   = lane >> 4;                   // k-octet

    f32x4 acc[4][4] = {};

    for (int tk = 0; tk < 12; ++tk) {
        const u16* asrc = (tk < 8) ? xhi : xlo;
        const int  kcol = (tk & 3) * 64;          // col in 256-wide source
        __syncthreads();
#pragma unroll
        for (int p = 0; p < 4; ++p) {
            const int c   = tid + p * 256;        // 0..1023 chunk id (8 bf16)
            const int row = c >> 3;
            const int ko  = (c & 7) * 8;
            const int di  = row * 64 + (ko ^ ((row & 7) << 3));
            *(uint4*)&As[di] = *(const uint4*)&asrc[(size_t)(m0 + row) * 256 + kcol + ko];
            *(uint4*)&Bs[di] = *(const uint4*)&BpT[(size_t)(n0 + row) * 768 + tk * 64 + ko];
        }
        __syncthreads();
#pragma unroll
        for (int kk = 0; kk < 2; ++kk) {
            s16x8 af[4], bfr[4];
            const int akw = kk * 32 + lk * 8;
#pragma unroll
            for (int i = 0; i < 4; ++i) {
                const int arow = wr * 64 + i * 16 + lr;
                af[i]  = *(const s16x8*)&As[arow * 64 + (akw ^ ((arow & 7) << 3))];
                const int brow = wc * 64 + i * 16 + lr;
                bfr[i] = *(const s16x8*)&Bs[brow * 64 + (akw ^ ((brow & 7) << 3))];
            }
#pragma unroll
            for (int i = 0; i < 4; ++i)
#pragma unroll
                for (int j = 0; j < 4; ++j)
                    acc[i][j] = __builtin_amdgcn_mfma_f32_16x16x32_bf16(
                        af[i], bfr[j], acc[i][j], 0, 0, 0);
        }
    }

    // Epilogue: C row = (lane>>4)*4 + r (+16*i), col = lr (+16*j); add bias.
    float* const outp = (n0 < 512) ? xl : xr;
    const int ocol0 = n0 & 511;
    const float* const bb = (n0 < 512) ? bl : br;
#pragma unroll
    for (int j = 0; j < 4; ++j) {
        const int col = ocol0 + wc * 64 + j * 16 + lr;
        const float bv = bb[col];
#pragma unroll
        for (int i = 0; i < 4; ++i) {
#pragma unroll
            for (int r = 0; r < 4; ++r) {
                const int rowg = m0 + wr * 64 + i * 16 + (lane >> 4) * 4 + r;
                outp[(size_t)rowg * 512 + col] = acc[i][j][r] + bv;
            }
        }
    }
}

// ---------------------------------------------------------------------------
// Counting sort of edges by dst
// ---------------------------------------------------------------------------
__global__ void k_hist(const int* __restrict__ ei, int* __restrict__ counts)
{
    int e = blockIdx.x * 256 + threadIdx.x;
    if (e < N_EDGES) atomicAdd(&counts[ei[N_EDGES + e]], 1);
}

__global__ __launch_bounds__(1024) void k_scan(
    const int* __restrict__ counts, int* __restrict__ offsets, int* __restrict__ cursors)
{
    __shared__ int part[1024];
    const int tid = threadIdx.x;
    const int base = tid * 32;
    int loc[32];
    int s = 0;
#pragma unroll
    for (int i = 0; i < 32; ++i) { loc[i] = s; s += counts[base + i]; }
    part[tid] = s;
    __syncthreads();
    const int own = s;
    for (int off = 1; off < 1024; off <<= 1) {
        int v = (tid >= off) ? part[tid - off] : 0;
        __syncthreads();
        part[tid] += v;
        __syncthreads();
    }
    const int pre = part[tid] - own;   // exclusive prefix of chunk
#pragma unroll
    for (int i = 0; i < 32; ++i) {
        int o = pre + loc[i];
        offsets[base + i] = o;
        cursors[base + i] = o;
    }
}

__global__ void k_scatter(const int* __restrict__ ei, int* __restrict__ cursors,
                          int* __restrict__ sorted_src, int* __restrict__ sorted_dst,
                          int* __restrict__ sorted_eid)
{
    int e = blockIdx.x * 256 + threadIdx.x;
    if (e >= N_EDGES) return;
    int d = ei[N_EDGES + e];
    int pos = atomicAdd(&cursors[d], 1);
    sorted_src[pos] = ei[e];
    sorted_dst[pos] = d;
    sorted_eid[pos] = e;
}

// ---------------------------------------------------------------------------
// k_alpha: per-edge logits. Lane owns 2 channels; 32-lane group owns a head.
// We fragment pinned into VGPRs via empty-asm (defeats remat/demotion).
// ---------------------------------------------------------------------------
#define EPB 32

__global__ __launch_bounds__(256, 4) void k_alpha(
    const float* __restrict__ xl, const float* __restrict__ xr,
    const float* __restrict__ ea, const float* __restrict__ We,
    const float* __restrict__ att,
    const int* __restrict__ sorted_src, const int* __restrict__ sorted_dst,
    const int* __restrict__ sorted_eid,
    float* __restrict__ logits)
{
    const int tid = threadIdx.x;
    const int c0 = tid * 2;
    const int head = tid >> 5;
    const int lead = ((tid & 31) == 0);

    float2 wr[32];
#pragma unroll
    for (int k = 0; k < 32; ++k)
        wr[k] = *(const float2*)&We[k * 512 + c0];
#pragma unroll
    for (int k = 0; k < 32; ++k)
        asm volatile("" : "+v"(wr[k].x), "+v"(wr[k].y));   // pin in VGPRs
    const float2 attv = *(const float2*)&att[c0];

    const int p0 = blockIdx.x * EPB;
    for (int j = 0; j < EPB; j += 2) {
        const int pA = p0 + j, pB = p0 + j + 1;
        const int sA = sorted_src[pA], sB = sorted_src[pB];
        const int dA = sorted_dst[pA], dB = sorted_dst[pB];
        const int eA = sorted_eid[pA], eB = sorted_eid[pB];
        const float2 xlA = *(const float2*)&xl[(size_t)sA * 512 + c0];
        const float2 xrA = *(const float2*)&xr[(size_t)dA * 512 + c0];
        const float2 xlB = *(const float2*)&xl[(size_t)sB * 512 + c0];
        const float2 xrB = *(const float2*)&xr[(size_t)dB * 512 + c0];
        const float* eaA = &ea[(size_t)eA * 32];
        const float* eaB = &ea[(size_t)eB * 32];

        float a0 = 0.f, a1 = 0.f, b0 = 0.f, b1 = 0.f;
#pragma unroll
        for (int k = 0; k < 32; ++k) {
            const float evA = eaA[k];
            const float evB = eaB[k];
            a0 += evA * wr[k].x; a1 += evA * wr[k].y;
            b0 += evB * wr[k].x; b1 += evB * wr[k].y;
        }
        float tA0 = xlA.x + xrA.x + a0; tA0 = tA0 > 0.f ? tA0 : NEG * tA0;
        float tA1 = xlA.y + xrA.y + a1; tA1 = tA1 > 0.f ? tA1 : NEG * tA1;
        float tB0 = xlB.x + xrB.x + b0; tB0 = tB0 > 0.f ? tB0 : NEG * tB0;
        float tB1 = xlB.y + xrB.y + b1; tB1 = tB1 > 0.f ? tB1 : NEG * tB1;

        float lA = tA0 * attv.x + tA1 * attv.y;
        float lB = tB0 * attv.x + tB1 * attv.y;
#pragma unroll
        for (int o = 1; o < 32; o <<= 1) {
            lA += __shfl_xor(lA, o);
            lB += __shfl_xor(lB, o);
        }
        if (lead) {
            logits[(size_t)pA * 8 + head] = lA;
            logits[(size_t)pB * 8 + head] = lB;
        }
    }
}

// ---------------------------------------------------------------------------
// k_agg: per-dst two-pass softmax + weighted xl[src] gather-sum, h, score.
// ---------------------------------------------------------------------------
#define AGG_DPB 8

__global__ __launch_bounds__(256, 8) void k_agg(
    const float* __restrict__ xl, const float* __restrict__ logits,
    const int* __restrict__ sorted_src,
    const int* __restrict__ offsets, const int* __restrict__ counts,
    const float* __restrict__ bias, const float* __restrict__ pw,
    float* __restrict__ h, float* __restrict__ score)
{
    __shared__ float red_s[4];

    const int tid = threadIdx.x;
    const int wv  = tid >> 6;
    const int l   = tid & 63;
    const int c0  = tid * 2;
    const int head = tid >> 5;

    const float2 bv  = *(const float2*)&bias[c0];
    const float2 pwv = *(const float2*)&pw[c0];

    float nrm = pwv.x * pwv.x + pwv.y * pwv.y;
#pragma unroll
    for (int o = 1; o < 64; o <<= 1) nrm += __shfl_xor(nrm, o);
    if (l == 0) red_s[wv] = nrm;
    __syncthreads();
    const float inv_nrm = 1.0f / sqrtf(red_s[0] + red_s[1] + red_s[2] + red_s[3]);

    for (int dd = 0; dd < AGG_DPB; ++dd) {
        const int d   = blockIdx.x * AGG_DPB + dd;
        const int off = offsets[d];
        const int deg = counts[d];

        float m = -INFINITY;
        for (int j = 0; j < deg; ++j)
            m = fmaxf(m, logits[(size_t)(off + j) * 8 + head]);

        float den = 0.f, a0 = 0.f, a1 = 0.f;
        for (int j = 0; j < deg; ++j) {
            const float lg = logits[(size_t)(off + j) * 8 + head];
            const int   s  = sorted_src[off + j];
            const float2 xl2 = *(const float2*)&xl[(size_t)s * 512 + c0];
            const float pe = __expf(lg - m);
            den += pe;
            a0 += pe * xl2.x;
            a1 += pe * xl2.y;
        }

        const float r = den > 0.f ? 1.0f / den : 0.f;
        const float h0 = fmaxf(a0 * r + bv.x, 0.f);
        const float h1 = fmaxf(a1 * r + bv.y, 0.f);
        *(float2*)&h[(size_t)d * 512 + c0] = make_float2(h0, h1);

        float ps = h0 * pwv.x + h1 * pwv.y;
#pragma unroll
        for (int o = 1; o < 64; o <<= 1) ps += __shfl_xor(ps, o);
        __syncthreads();
        if (l == 0) red_s[wv] = ps;
        __syncthreads();
        if (tid == 0)
            score[d] = tanhf((red_s[0] + red_s[1] + red_s[2] + red_s[3]) * inv_nrm);
    }
}

// ---------------------------------------------------------------------------
// Per-graph top-K via bitonic sort of packed keys (score desc, idx asc)
// ---------------------------------------------------------------------------
__global__ __launch_bounds__(256) void k_topk(const float* __restrict__ score,
                                              int* __restrict__ sel_idx,
                                              float* __restrict__ sel_val)
{
    __shared__ unsigned long long key[1024];
    const int g = blockIdx.x, tid = threadIdx.x;
    for (int i = tid; i < 1024; i += 256) {
        float s = score[g * 1024 + i];
        unsigned u = __float_as_uint(s);
        u = (u & 0x80000000u) ? ~u : (u | 0x80000000u);   // orderable, ascending
        key[i] = ((unsigned long long)(~u) << 32) | (unsigned)i;  // asc key == desc score
    }
    __syncthreads();
    for (int k = 2; k <= 1024; k <<= 1) {
        for (int j = k >> 1; j > 0; j >>= 1) {
            for (int i = tid; i < 1024; i += 256) {
                int ixj = i ^ j;
                if (ixj > i) {
                    bool up = ((i & k) == 0);
                    unsigned long long a = key[i], b = key[ixj];
                    if ((a > b) == up) { key[i] = b; key[ixj] = a; }
                }
            }
            __syncthreads();
        }
    }
    for (int kk = tid; kk < KSEL; kk += 256) {
        int idx = (int)(key[kk] & 0xFFFFFFFFu);
        sel_idx[g * KSEL + kk] = idx;
        sel_val[g * KSEL + kk] = score[g * 1024 + idx];
    }
}

// ---------------------------------------------------------------------------
// Pool: gmp = max_k(h[idx_k]*val_k), gap = mean_k(...) — k-sliced + merge
// ---------------------------------------------------------------------------
#define KSLICE 103

__global__ __launch_bounds__(256) void k_pool_part(
    const float* __restrict__ h, const int* __restrict__ sel_idx,
    const float* __restrict__ sel_val, float* __restrict__ part)
{
    const int g = blockIdx.x >> 3, sl = blockIdx.x & 7;
    const int kbeg = sl * KSLICE;
    const int kend = min(KSEL, kbeg + KSLICE);
    const int n = kend - kbeg;
    __shared__ float vs[KSLICE];
    __shared__ int   is_[KSLICE];
    const int tid = threadIdx.x;
    if (tid < n) {
        vs[tid]  = sel_val[g * KSEL + kbeg + tid];
        is_[tid] = sel_idx[g * KSEL + kbeg + tid];
    }
    __syncthreads();
    const int c0 = tid, c1 = tid + 256;
    float mx0 = -INFINITY, mx1 = -INFINITY, s0 = 0.f, s1 = 0.f;
    for (int kk = 0; kk < n; ++kk) {
        const float* hp = h + ((size_t)(g * 1024 + is_[kk])) * 512;
        const float v = vs[kk];
        float f0 = hp[c0] * v, f1 = hp[c1] * v;
        mx0 = fmaxf(mx0, f0); s0 += f0;
        mx1 = fmaxf(mx1, f1); s1 += f1;
    }
    const size_t base = ((size_t)blockIdx.x * 2) * 512;
    part[base + c0] = mx0;        part[base + c1] = mx1;
    part[base + 512 + c0] = s0;   part[base + 512 + c1] = s1;
}

__global__ __launch_bounds__(256) void k_pool_merge(
    const float* __restrict__ part, float* __restrict__ out)
{
    const int g = blockIdx.x, tid = threadIdx.x;
    const int c0 = tid, c1 = tid + 256;
    float mx0 = -INFINITY, mx1 = -INFINITY, s0 = 0.f, s1 = 0.f;
    for (int sl = 0; sl < 8; ++sl) {
        const size_t base = ((size_t)(g * 8 + sl) * 2) * 512;
        mx0 = fmaxf(mx0, part[base + c0]); mx1 = fmaxf(mx1, part[base + c1]);
        s0 += part[base + 512 + c0];       s1 += part[base + 512 + c1];
    }
    out[(size_t)g * 1024 + c0] = mx0;
    out[(size_t)g * 1024 + c1] = mx1;
    out[(size_t)g * 1024 + 512 + c0] = s0 * (1.f / KSEL);
    out[(size_t)g * 1024 + 512 + c1] = s1 * (1.f / KSEL);
}

// ---------------------------------------------------------------------------
extern "C" void kernel_launch(void* const* d_in, const int* in_sizes, int n_in,
                              void* d_out, int out_size, void* d_ws, size_t ws_size,
                              hipStream_t stream)
{
    const float* x    = (const float*)d_in[0];
    const float* ea   = (const float*)d_in[1];
    const float* Wl   = (const float*)d_in[2];
    const float* bl   = (const float*)d_in[3];
    const float* Wr   = (const float*)d_in[4];
    const float* br   = (const float*)d_in[5];
    const float* We   = (const float*)d_in[6];
    const float* att  = (const float*)d_in[7];
    const float* bias = (const float*)d_in[8];
    const float* pw   = (const float*)d_in[9];
    const int*   ei   = (const int*)d_in[10];
    float* out = (float*)d_out;

    // workspace layout (4B units unless noted)
    float* xl        = (float*)d_ws;                      // N*512
    float* xr        = xl + (size_t)N_NODES * 512;
    float* h         = xr + (size_t)N_NODES * 512;
    float* logits    = h + (size_t)N_NODES * 512;         // E*8
    float* sel_val   = logits + (size_t)N_EDGES * 8;      // 32*820
    float* part      = sel_val + BGRAPH * KSEL;           // 256*2*512
    float* score     = part + 256 * 2 * 512;              // 32768
    int* counts      = (int*)(score + N_NODES);
    int* offsets     = counts + N_NODES;
    int* cursors     = offsets + N_NODES;
    int* sorted_src  = cursors + N_NODES;                 // E
    int* sorted_dst  = sorted_src + N_EDGES;              // E
    int* sorted_eid  = sorted_dst + N_EDGES;              // E
    int* sel_idx     = sorted_eid + N_EDGES;              // 32*820
    u16* xhi         = (u16*)(sel_idx + BGRAPH * KSEL);   // N*256 u16
    u16* xlo         = xhi + (size_t)N_NODES * 256;       // N*256 u16
    u16* bpt         = xlo + (size_t)N_NODES * 256;       // 1024*768 u16

    hipMemsetAsync(counts, 0, (size_t)N_NODES * sizeof(int), stream);

    k_split_x<<<(N_NODES * 256) / (4 * 256), 256, 0, stream>>>(x, xhi, xlo);
    k_pack_bt<<<dim3(3, 1024), 256, 0, stream>>>(Wl, Wr, bpt);
    gemm_mfma<<<2048, 256, 0, stream>>>(xhi, xlo, bpt, bl, br, xl, xr);

    k_hist<<<N_EDGES / 256, 256, 0, stream>>>(ei, counts);
    k_scan<<<1, 1024, 0, stream>>>(counts, offsets, cursors);
    k_scatter<<<N_EDGES / 256, 256, 0, stream>>>(ei, cursors, sorted_src, sorted_dst, sorted_eid);
    k_alpha<<<N_EDGES / EPB, 256, 0, stream>>>(xl, xr, ea, We, att,
                                               sorted_src, sorted_dst, sorted_eid, logits);
    k_agg<<<N_NODES / AGG_DPB, 256, 0, stream>>>(xl, logits, sorted_src, offsets, counts,
                                                 bias, pw, h, score);
    k_topk<<<BGRAPH, 256, 0, stream>>>(score, sel_idx, sel_val);
    k_pool_part<<<BGRAPH * 8, 256, 0, stream>>>(h, sel_idx, sel_val, part);
    k_pool_merge<<<BGRAPH, 256, 0, stream>>>(part, out);
}

// Round 8
// 605.305 us; speedup vs baseline: 1.2292x; 1.1229x over previous
//
#include <hip/hip_runtime.h>
#include <hip/hip_bf16.h>
#include <cstdint>
#include <cstddef>

#define N_NODES 32768
#define N_EDGES 262144
#define BGRAPH  32
#define NPG     1024
#define KSEL    820
#define NEG     0.2f

typedef unsigned short u16;
typedef __attribute__((ext_vector_type(4))) float f32x4;
typedef __attribute__((ext_vector_type(8))) short s16x8;

static __device__ __forceinline__ u16 f2bf(float v) {
    __hip_bfloat16 b(v);
    return *reinterpret_cast<u16*>(&b);
}
static __device__ __forceinline__ float bf2f(u16 u) {
    __hip_bfloat16 b = *reinterpret_cast<__hip_bfloat16*>(&u);
    return (float)b;
}

typedef const __attribute__((address_space(1))) void* gas_p;
typedef __attribute__((address_space(3))) void* las_p;
static __device__ __forceinline__ void gload16(const void* g, void* l) {
    __builtin_amdgcn_global_load_lds((gas_p)g, (las_p)l, 16, 0, 0);
}

// ---------------------------------------------------------------------------
// Prep: split x into bf16 hi/lo (x = hi + lo + eps, eps ~ 2^-16 rel)
// ---------------------------------------------------------------------------
__global__ __launch_bounds__(256) void k_split_x(
    const float* __restrict__ x, u16* __restrict__ xhi, u16* __restrict__ xlo)
{
    const int i = blockIdx.x * 256 + threadIdx.x;      // one float4 per thread
    const float4 v = *(const float4*)&x[(size_t)i * 4];
    u16 h0 = f2bf(v.x), h1 = f2bf(v.y), h2 = f2bf(v.z), h3 = f2bf(v.w);
    u16 l0 = f2bf(v.x - bf2f(h0));
    u16 l1 = f2bf(v.y - bf2f(h1));
    u16 l2 = f2bf(v.z - bf2f(h2));
    u16 l3 = f2bf(v.w - bf2f(h3));
    *(ushort4*)&xhi[(size_t)i * 4] = make_ushort4(h0, h1, h2, h3);
    *(ushort4*)&xlo[(size_t)i * 4] = make_ushort4(l0, l1, l2, l3);
}

// ---------------------------------------------------------------------------
// Prep: packed transposed B' [1024 n][768 k'] bf16.
//   k'<256: hi(W[k']) ; 256..511: lo(W[k'-256]) ; >=512: hi(W[k'-512])
//   n<512 -> Wl, else Wr.
// ---------------------------------------------------------------------------
__global__ __launch_bounds__(256) void k_pack_bt(
    const float* __restrict__ Wl, const float* __restrict__ Wr,
    u16* __restrict__ BpT)
{
    const int kp = blockIdx.x * 256 + threadIdx.x;     // 0..767 (grid.x = 3)
    const int n  = blockIdx.y;                         // 0..1023
    if (kp >= 768) return;
    const float* W = (n < 512) ? Wl : Wr;
    const int col = n & 511;
    const int k = kp & 255;
    const float v = W[(size_t)k * 512 + col];
    const u16 h = f2bf(v);
    const u16 o = (kp >= 256 && kp < 512) ? f2bf(v - bf2f(h)) : h;
    BpT[(size_t)n * 768 + kp] = o;
}

// ---------------------------------------------------------------------------
// Split-bf16 MFMA GEMM: C[32768 x 1024] = A'[M x 768] @ B'[768 x 1024] + bias
// Staging via global_load_lds(16B): linear LDS dest + inverse-swizzled GLOBAL
// source (content identical to the old reg-staged XOR layout; read path
// unchanged from the passing round-5 kernel).
// ---------------------------------------------------------------------------
__global__ __launch_bounds__(256) void gemm_mfma(
    const u16* __restrict__ xhi, const u16* __restrict__ xlo,
    const u16* __restrict__ BpT,
    const float* __restrict__ bl, const float* __restrict__ br,
    float* __restrict__ xl, float* __restrict__ xr)
{
    __shared__ u16 As[128 * 64];
    __shared__ u16 Bs[128 * 64];

    // XCD-aware swizzle: 2048 blocks, 8 XCDs -> each XCD owns one N-tile.
    const int raw = blockIdx.x;
    const int swz = (raw & 7) * 256 + (raw >> 3);
    const int mt = swz & 255, nt = swz >> 8;
    const int m0 = mt * 128, n0 = nt * 128;

    const int tid  = threadIdx.x;
    const int lane = tid & 63;
    const int wid  = tid >> 6;
    const int wr   = wid >> 1, wc = wid & 1;      // 64x64 wave tile
    const int lr   = lane & 15;                   // frag row/col
    const int lk   = lane >> 4;                   // k-octet

    f32x4 acc[4][4] = {};

    for (int tk = 0; tk < 12; ++tk) {
        const u16* asrc = (tk < 8) ? xhi : xlo;
        const int  kcol = (tk & 3) * 64;          // col in 256-wide source
        __syncthreads();
#pragma unroll
        for (int p = 0; p < 4; ++p) {
            const int c   = p * 256 + wid * 64 + lane;   // chunk 0..1023
            const int row = c >> 3;
            const int cs  = ((c & 7) ^ (row & 7)) * 8;   // swizzled src chunk (u16)
            gload16(&asrc[(size_t)(m0 + row) * 256 + kcol + cs],
                    &As[(size_t)(p * 256 + wid * 64) * 8]);
            gload16(&BpT[(size_t)(n0 + row) * 768 + tk * 64 + cs],
                    &Bs[(size_t)(p * 256 + wid * 64) * 8]);
        }
        __syncthreads();
#pragma unroll
        for (int kk = 0; kk < 2; ++kk) {
            s16x8 af[4], bfr[4];
            const int akw = kk * 32 + lk * 8;
#pragma unroll
            for (int i = 0; i < 4; ++i) {
                const int arow = wr * 64 + i * 16 + lr;
                af[i]  = *(const s16x8*)&As[arow * 64 + (akw ^ ((arow & 7) << 3))];
                const int brow = wc * 64 + i * 16 + lr;
                bfr[i] = *(const s16x8*)&Bs[brow * 64 + (akw ^ ((brow & 7) << 3))];
            }
#pragma unroll
            for (int i = 0; i < 4; ++i)
#pragma unroll
                for (int j = 0; j < 4; ++j)
                    acc[i][j] = __builtin_amdgcn_mfma_f32_16x16x32_bf16(
                        af[i], bfr[j], acc[i][j], 0, 0, 0);
        }
    }

    // Epilogue: C row = (lane>>4)*4 + r (+16*i), col = lr (+16*j); add bias.
    float* const outp = (n0 < 512) ? xl : xr;
    const int ocol0 = n0 & 511;
    const float* const bb = (n0 < 512) ? bl : br;
#pragma unroll
    for (int j = 0; j < 4; ++j) {
        const int col = ocol0 + wc * 64 + j * 16 + lr;
        const float bv = bb[col];
#pragma unroll
        for (int i = 0; i < 4; ++i) {
#pragma unroll
            for (int r = 0; r < 4; ++r) {
                const int rowg = m0 + wr * 64 + i * 16 + (lane >> 4) * 4 + r;
                outp[(size_t)rowg * 512 + col] = acc[i][j][r] + bv;
            }
        }
    }
}

// ---------------------------------------------------------------------------
// Counting sort of edges by dst
// ---------------------------------------------------------------------------
__global__ void k_hist(const int* __restrict__ ei, int* __restrict__ counts)
{
    int e = blockIdx.x * 256 + threadIdx.x;
    if (e < N_EDGES) atomicAdd(&counts[ei[N_EDGES + e]], 1);
}

__global__ __launch_bounds__(1024) void k_scan(
    const int* __restrict__ counts, int* __restrict__ offsets, int* __restrict__ cursors)
{
    __shared__ int part[1024];
    const int tid = threadIdx.x;
    const int base = tid * 32;
    int loc[32];
    int s = 0;
#pragma unroll
    for (int i = 0; i < 32; ++i) { loc[i] = s; s += counts[base + i]; }
    part[tid] = s;
    __syncthreads();
    const int own = s;
    for (int off = 1; off < 1024; off <<= 1) {
        int v = (tid >= off) ? part[tid - off] : 0;
        __syncthreads();
        part[tid] += v;
        __syncthreads();
    }
    const int pre = part[tid] - own;   // exclusive prefix of chunk
#pragma unroll
    for (int i = 0; i < 32; ++i) {
        int o = pre + loc[i];
        offsets[base + i] = o;
        cursors[base + i] = o;
    }
}

__global__ void k_scatter(const int* __restrict__ ei, int* __restrict__ cursors,
                          int* __restrict__ sorted_src, int* __restrict__ sorted_dst,
                          int* __restrict__ sorted_eid)
{
    int e = blockIdx.x * 256 + threadIdx.x;
    if (e >= N_EDGES) return;
    int d = ei[N_EDGES + e];
    int pos = atomicAdd(&cursors[d], 1);
    sorted_src[pos] = ei[e];
    sorted_dst[pos] = d;
    sorted_eid[pos] = e;
}

// ---------------------------------------------------------------------------
// k_logit: per-edge logits via MFMA.
// Tile = 64 edges x 128 channels (blockIdx.y = channel slab -> heads 2s,2s+1).
// edot = ea[64x32] @ We[32x128] as split-bf16 K'=96 (A'=[hi|lo|hi],
// B'=[hi|hi|lo]), both operands in LDS. Epilogue: z = edot + xl[src] + xr[dst]
// (gathered, 64B-coalesced per 16-lane group), lrelu, att-weighted 16-lane
// reduce -> logits[E][8] (slabs write disjoint head pairs).
// ---------------------------------------------------------------------------
#define LT_TILES 8

__global__ __launch_bounds__(256, 4) void k_logit(
    const float* __restrict__ xl, const float* __restrict__ xr,
    const float* __restrict__ ea, const float* __restrict__ We,
    const float* __restrict__ att,
    const int* __restrict__ sorted_src, const int* __restrict__ sorted_dst,
    const int* __restrict__ sorted_eid,
    float* __restrict__ logits)
{
    __shared__ u16 Ws[128 * 104];
    __shared__ u16 Ae[64 * 104];
    __shared__ int eid_s[64], src_s[64], dst_s[64];

    const int tid  = threadIdx.x;
    const int lane = tid & 63;
    const int wid  = tid >> 6;
    const int slab = blockIdx.y;                 // 0..3
    const int lr   = lane & 15;
    const int lk   = lane >> 4;

    // Stage We slab: Ws[ch(128)][kp(96), pad 104]; kp<64 -> hi, >=64 -> lo.
    for (int idx = tid; idx < 128 * 96; idx += 256) {
        const int ch = idx / 96, kp = idx % 96;
        const int k = (kp < 32) ? kp : ((kp < 64) ? kp - 32 : kp - 64);
        const float v = We[(size_t)k * 512 + slab * 128 + ch];
        const u16 h = f2bf(v);
        Ws[ch * 104 + kp] = (kp >= 64) ? f2bf(v - bf2f(h)) : h;
    }
    float attw[8];
#pragma unroll
    for (int f = 0; f < 8; ++f) attw[f] = att[slab * 128 + f * 16 + lr];

    for (int t = 0; t < LT_TILES; ++t) {
        const int ebase = (blockIdx.x * LT_TILES + t) * 64;
        __syncthreads();                          // Ae/meta safe to overwrite
        if (tid < 64) {
            eid_s[tid] = sorted_eid[ebase + tid];
            src_s[tid] = sorted_src[ebase + tid];
            dst_s[tid] = sorted_dst[ebase + tid];
        }
        __syncthreads();
        // Stage ea tile: Ae[64 e][kp 96]: kp<32 hi, 32..63 lo, 64..95 hi.
        for (int idx = tid; idx < 64 * 32; idx += 256) {
            const int r = idx >> 5, k = idx & 31;
            const float v = ea[(size_t)eid_s[r] * 32 + k];
            const u16 h = f2bf(v);
            Ae[r * 104 + k]      = h;
            Ae[r * 104 + 32 + k] = f2bf(v - bf2f(h));
            Ae[r * 104 + 64 + k] = h;
        }
        __syncthreads();

        // MFMA: wave wid owns edges ebase + wid*16 .. +15.
        f32x4 acc[8] = {};
#pragma unroll
        for (int ks = 0; ks < 3; ++ks) {
            const s16x8 afr = *(const s16x8*)&Ae[(wid * 16 + lr) * 104 + ks * 32 + lk * 8];
#pragma unroll
            for (int f = 0; f < 8; ++f) {
                const s16x8 bfr = *(const s16x8*)&Ws[(f * 16 + lr) * 104 + ks * 32 + lk * 8];
                acc[f] = __builtin_amdgcn_mfma_f32_16x16x32_bf16(afr, bfr, acc[f], 0, 0, 0);
            }
        }

        // Epilogue: z = acc + xl[src] + xr[dst]; lrelu; att-weighted sums.
        float p0[4], p1[4];
#pragma unroll
        for (int r = 0; r < 4; ++r) { p0[r] = 0.f; p1[r] = 0.f; }
#pragma unroll
        for (int r = 0; r < 4; ++r) {
            const int el = wid * 16 + lk * 4 + r;           // local edge 0..63
            const size_t sb = (size_t)src_s[el] * 512 + slab * 128 + lr;
            const size_t db = (size_t)dst_s[el] * 512 + slab * 128 + lr;
#pragma unroll
            for (int f = 0; f < 8; ++f) {
                const float z = acc[f][r] + xl[sb + f * 16] + xr[db + f * 16];
                const float tt = z > 0.f ? z : NEG * z;
                if (f < 4) p0[r] += attw[f] * tt;
                else       p1[r] += attw[f] * tt;
            }
        }
#pragma unroll
        for (int o = 1; o < 16; o <<= 1) {
#pragma unroll
            for (int r = 0; r < 4; ++r) {
                p0[r] += __shfl_xor(p0[r], o);
                p1[r] += __shfl_xor(p1[r], o);
            }
        }
        if (lr == 0) {
#pragma unroll
            for (int r = 0; r < 4; ++r) {
                const size_t eg = ebase + wid * 16 + lk * 4 + r;
                logits[eg * 8 + slab * 2]     = p0[r];
                logits[eg * 8 + slab * 2 + 1] = p1[r];
            }
        }
    }
}

// ---------------------------------------------------------------------------
// k_agg: per-dst two-pass softmax + weighted xl[src] gather-sum, h, score.
// ---------------------------------------------------------------------------
#define AGG_DPB 8

__global__ __launch_bounds__(256, 8) void k_agg(
    const float* __restrict__ xl, const float* __restrict__ logits,
    const int* __restrict__ sorted_src,
    const int* __restrict__ offsets, const int* __restrict__ counts,
    const float* __restrict__ bias, const float* __restrict__ pw,
    float* __restrict__ h, float* __restrict__ score)
{
    __shared__ float red_s[4];

    const int tid = threadIdx.x;
    const int wv  = tid >> 6;
    const int l   = tid & 63;
    const int c0  = tid * 2;
    const int head = tid >> 5;

    const float2 bv  = *(const float2*)&bias[c0];
    const float2 pwv = *(const float2*)&pw[c0];

    float nrm = pwv.x * pwv.x + pwv.y * pwv.y;
#pragma unroll
    for (int o = 1; o < 64; o <<= 1) nrm += __shfl_xor(nrm, o);
    if (l == 0) red_s[wv] = nrm;
    __syncthreads();
    const float inv_nrm = 1.0f / sqrtf(red_s[0] + red_s[1] + red_s[2] + red_s[3]);

    for (int dd = 0; dd < AGG_DPB; ++dd) {
        const int d   = blockIdx.x * AGG_DPB + dd;
        const int off = offsets[d];
        const int deg = counts[d];

        float m = -INFINITY;
        for (int j = 0; j < deg; ++j)
            m = fmaxf(m, logits[(size_t)(off + j) * 8 + head]);

        float den = 0.f, a0 = 0.f, a1 = 0.f;
        for (int j = 0; j < deg; ++j) {
            const float lg = logits[(size_t)(off + j) * 8 + head];
            const int   s  = sorted_src[off + j];
            const float2 xl2 = *(const float2*)&xl[(size_t)s * 512 + c0];
            const float pe = __expf(lg - m);
            den += pe;
            a0 += pe * xl2.x;
            a1 += pe * xl2.y;
        }

        const float r = den > 0.f ? 1.0f / den : 0.f;
        const float h0 = fmaxf(a0 * r + bv.x, 0.f);
        const float h1 = fmaxf(a1 * r + bv.y, 0.f);
        *(float2*)&h[(size_t)d * 512 + c0] = make_float2(h0, h1);

        float ps = h0 * pwv.x + h1 * pwv.y;
#pragma unroll
        for (int o = 1; o < 64; o <<= 1) ps += __shfl_xor(ps, o);
        __syncthreads();
        if (l == 0) red_s[wv] = ps;
        __syncthreads();
        if (tid == 0)
            score[d] = tanhf((red_s[0] + red_s[1] + red_s[2] + red_s[3]) * inv_nrm);
    }
}

// ---------------------------------------------------------------------------
// Per-graph top-K via bitonic sort of packed keys (score desc, idx asc)
// ---------------------------------------------------------------------------
__global__ __launch_bounds__(256) void k_topk(const float* __restrict__ score,
                                              int* __restrict__ sel_idx,
                                              float* __restrict__ sel_val)
{
    __shared__ unsigned long long key[1024];
    const int g = blockIdx.x, tid = threadIdx.x;
    for (int i = tid; i < 1024; i += 256) {
        float s = score[g * 1024 + i];
        unsigned u = __float_as_uint(s);
        u = (u & 0x80000000u) ? ~u : (u | 0x80000000u);   // orderable, ascending
        key[i] = ((unsigned long long)(~u) << 32) | (unsigned)i;  // asc key == desc score
    }
    __syncthreads();
    for (int k = 2; k <= 1024; k <<= 1) {
        for (int j = k >> 1; j > 0; j >>= 1) {
            for (int i = tid; i < 1024; i += 256) {
                int ixj = i ^ j;
                if (ixj > i) {
                    bool up = ((i & k) == 0);
                    unsigned long long a = key[i], b = key[ixj];
                    if ((a > b) == up) { key[i] = b; key[ixj] = a; }
                }
            }
            __syncthreads();
        }
    }
    for (int kk = tid; kk < KSEL; kk += 256) {
        int idx = (int)(key[kk] & 0xFFFFFFFFu);
        sel_idx[g * KSEL + kk] = idx;
        sel_val[g * KSEL + kk] = score[g * 1024 + idx];
    }
}

// ---------------------------------------------------------------------------
// Pool: gmp = max_k(h[idx_k]*val_k), gap = mean_k(...) — k-sliced + merge
// ---------------------------------------------------------------------------
#define KSLICE 103

__global__ __launch_bounds__(256) void k_pool_part(
    const float* __restrict__ h, const int* __restrict__ sel_idx,
    const float* __restrict__ sel_val, float* __restrict__ part)
{
    const int g = blockIdx.x >> 3, sl = blockIdx.x & 7;
    const int kbeg = sl * KSLICE;
    const int kend = min(KSEL, kbeg + KSLICE);
    const int n = kend - kbeg;
    __shared__ float vs[KSLICE];
    __shared__ int   is_[KSLICE];
    const int tid = threadIdx.x;
    if (tid < n) {
        vs[tid]  = sel_val[g * KSEL + kbeg + tid];
        is_[tid] = sel_idx[g * KSEL + kbeg + tid];
    }
    __syncthreads();
    const int c0 = tid, c1 = tid + 256;
    float mx0 = -INFINITY, mx1 = -INFINITY, s0 = 0.f, s1 = 0.f;
    for (int kk = 0; kk < n; ++kk) {
        const float* hp = h + ((size_t)(g * 1024 + is_[kk])) * 512;
        const float v = vs[kk];
        float f0 = hp[c0] * v, f1 = hp[c1] * v;
        mx0 = fmaxf(mx0, f0); s0 += f0;
        mx1 = fmaxf(mx1, f1); s1 += f1;
    }
    const size_t base = ((size_t)blockIdx.x * 2) * 512;
    part[base + c0] = mx0;        part[base + c1] = mx1;
    part[base + 512 + c0] = s0;   part[base + 512 + c1] = s1;
}

__global__ __launch_bounds__(256) void k_pool_merge(
    const float* __restrict__ part, float* __restrict__ out)
{
    const int g = blockIdx.x, tid = threadIdx.x;
    const int c0 = tid, c1 = tid + 256;
    float mx0 = -INFINITY, mx1 = -INFINITY, s0 = 0.f, s1 = 0.f;
    for (int sl = 0; sl < 8; ++sl) {
        const size_t base = ((size_t)(g * 8 + sl) * 2) * 512;
        mx0 = fmaxf(mx0, part[base + c0]); mx1 = fmaxf(mx1, part[base + c1]);
        s0 += part[base + 512 + c0];       s1 += part[base + 512 + c1];
    }
    out[(size_t)g * 1024 + c0] = mx0;
    out[(size_t)g * 1024 + c1] = mx1;
    out[(size_t)g * 1024 + 512 + c0] = s0 * (1.f / KSEL);
    out[(size_t)g * 1024 + 512 + c1] = s1 * (1.f / KSEL);
}

// ---------------------------------------------------------------------------
extern "C" void kernel_launch(void* const* d_in, const int* in_sizes, int n_in,
                              void* d_out, int out_size, void* d_ws, size_t ws_size,
                              hipStream_t stream)
{
    const float* x    = (const float*)d_in[0];
    const float* ea   = (const float*)d_in[1];
    const float* Wl   = (const float*)d_in[2];
    const float* bl   = (const float*)d_in[3];
    const float* Wr   = (const float*)d_in[4];
    const float* br   = (const float*)d_in[5];
    const float* We   = (const float*)d_in[6];
    const float* att  = (const float*)d_in[7];
    const float* bias = (const float*)d_in[8];
    const float* pw   = (const float*)d_in[9];
    const int*   ei   = (const int*)d_in[10];
    float* out = (float*)d_out;

    // workspace layout (4B units unless noted)
    float* xl        = (float*)d_ws;                      // N*512
    float* xr        = xl + (size_t)N_NODES * 512;
    float* h         = xr + (size_t)N_NODES * 512;
    float* logits    = h + (size_t)N_NODES * 512;         // E*8
    float* sel_val   = logits + (size_t)N_EDGES * 8;      // 32*820
    float* part      = sel_val + BGRAPH * KSEL;           // 256*2*512
    float* score     = part + 256 * 2 * 512;              // 32768
    int* counts      = (int*)(score + N_NODES);
    int* offsets     = counts + N_NODES;
    int* cursors     = offsets + N_NODES;
    int* sorted_src  = cursors + N_NODES;                 // E
    int* sorted_dst  = sorted_src + N_EDGES;              // E
    int* sorted_eid  = sorted_dst + N_EDGES;              // E
    int* sel_idx     = sorted_eid + N_EDGES;              // 32*820
    u16* xhi         = (u16*)(sel_idx + BGRAPH * KSEL);   // N*256 u16
    u16* xlo         = xhi + (size_t)N_NODES * 256;       // N*256 u16
    u16* bpt         = xlo + (size_t)N_NODES * 256;       // 1024*768 u16

    hipMemsetAsync(counts, 0, (size_t)N_NODES * sizeof(int), stream);

    k_split_x<<<(N_NODES * 256) / (4 * 256), 256, 0, stream>>>(x, xhi, xlo);
    k_pack_bt<<<dim3(3, 1024), 256, 0, stream>>>(Wl, Wr, bpt);
    gemm_mfma<<<2048, 256, 0, stream>>>(xhi, xlo, bpt, bl, br, xl, xr);

    k_hist<<<N_EDGES / 256, 256, 0, stream>>>(ei, counts);
    k_scan<<<1, 1024, 0, stream>>>(counts, offsets, cursors);
    k_scatter<<<N_EDGES / 256, 256, 0, stream>>>(ei, cursors, sorted_src, sorted_dst, sorted_eid);
    k_logit<<<dim3(N_EDGES / 64 / LT_TILES, 4), 256, 0, stream>>>(
        xl, xr, ea, We, att, sorted_src, sorted_dst, sorted_eid, logits);
    k_agg<<<N_NODES / AGG_DPB, 256, 0, stream>>>(xl, logits, sorted_src, offsets, counts,
                                                 bias, pw, h, score);
    k_topk<<<BGRAPH, 256, 0, stream>>>(score, sel_idx, sel_val);
    k_pool_part<<<BGRAPH * 8, 256, 0, stream>>>(h, sel_idx, sel_val, part);
    k_pool_merge<<<BGRAPH, 256, 0, stream>>>(part, out);
}

// Round 9
// 589.883 us; speedup vs baseline: 1.2614x; 1.0261x over previous
//
#include <hip/hip_runtime.h>
#include <hip/hip_bf16.h>
#include <cstdint>
#include <cstddef>

#define N_NODES 32768
#define N_EDGES 262144
#define BGRAPH  32
#define NPG     1024
#define KSEL    820
#define NEG     0.2f

typedef unsigned short u16;
typedef __attribute__((ext_vector_type(4))) float f32x4;
typedef __attribute__((ext_vector_type(8))) short s16x8;

static __device__ __forceinline__ u16 f2bf(float v) {
    __hip_bfloat16 b(v);
    return *reinterpret_cast<u16*>(&b);
}
static __device__ __forceinline__ float bf2f(u16 u) {
    __hip_bfloat16 b = *reinterpret_cast<__hip_bfloat16*>(&u);
    return (float)b;
}

typedef const __attribute__((address_space(1))) void* gas_p;
typedef __attribute__((address_space(3))) void* las_p;
static __device__ __forceinline__ void gload16(const void* g, void* l) {
    __builtin_amdgcn_global_load_lds((gas_p)g, (las_p)l, 16, 0, 0);
}

// ---------------------------------------------------------------------------
// Prep: split x into bf16 hi/lo (x = hi + lo + eps, eps ~ 2^-16 rel)
// ---------------------------------------------------------------------------
__global__ __launch_bounds__(256) void k_split_x(
    const float* __restrict__ x, u16* __restrict__ xhi, u16* __restrict__ xlo)
{
    const int i = blockIdx.x * 256 + threadIdx.x;      // one float4 per thread
    const float4 v = *(const float4*)&x[(size_t)i * 4];
    u16 h0 = f2bf(v.x), h1 = f2bf(v.y), h2 = f2bf(v.z), h3 = f2bf(v.w);
    u16 l0 = f2bf(v.x - bf2f(h0));
    u16 l1 = f2bf(v.y - bf2f(h1));
    u16 l2 = f2bf(v.z - bf2f(h2));
    u16 l3 = f2bf(v.w - bf2f(h3));
    *(ushort4*)&xhi[(size_t)i * 4] = make_ushort4(h0, h1, h2, h3);
    *(ushort4*)&xlo[(size_t)i * 4] = make_ushort4(l0, l1, l2, l3);
}

// ---------------------------------------------------------------------------
// Prep: packed transposed B' [1024 n][512 k'] bf16: k'<256 hi(W[k']),
// k'>=256 lo(W[k'-256]). n<512 -> Wl, else Wr.
// ---------------------------------------------------------------------------
__global__ __launch_bounds__(256) void k_pack_bt(
    const float* __restrict__ Wl, const float* __restrict__ Wr,
    u16* __restrict__ BpT)
{
    const int kp = blockIdx.x * 256 + threadIdx.x;     // 0..511 (grid.x = 2)
    const int n  = blockIdx.y;                         // 0..1023
    const float* W = (n < 512) ? Wl : Wr;
    const int col = n & 511;
    const int k = kp & 255;
    const float v = W[(size_t)k * 512 + col];
    const u16 h = f2bf(v);
    const u16 o = (kp >= 256) ? f2bf(v - bf2f(h)) : h;
    BpT[(size_t)n * 512 + kp] = o;
}

// ---------------------------------------------------------------------------
// Prep: webf[slab][ch 128][32] bf16 = We[.][slab*128+ch] with per-row chunk
// swizzle baked in: webf[slab][ch][c*8+j] = We[(c^s(ch))*8 + j][slab*128+ch],
// s(row) = (row&3) ^ ((row>>2)&3). k_logit stages it with linear gload16 and
// reads chunk (lk ^ s) -> bank-spread, correct contents.
// ---------------------------------------------------------------------------
__global__ __launch_bounds__(256) void k_prep_we(
    const float* __restrict__ We, u16* __restrict__ webf)
{
    const int g = blockIdx.x * 256 + threadIdx.x;      // 0..16383 (64 blocks)
    const int slab = g >> 12, ch = (g >> 5) & 127, kk = g & 31;
    const int c = kk >> 3, j = kk & 7;
    const int s = (ch & 3) ^ ((ch >> 2) & 3);
    const int ksrc = ((c ^ s) << 3) + j;
    webf[g] = f2bf(We[(size_t)ksrc * 512 + slab * 128 + ch]);
}

// ---------------------------------------------------------------------------
// Split-bf16 MFMA GEMM: C[32768 x 1024] = A'[M x 512+] @ B' + bias, as
// Ahi*Bhi + Ahi*Blo + Alo*Bhi per 32-K slice. All 4 operands staged per slice
// (4 x 8KB LDS) via gload16 with inverse-swizzled global source; 48 MFMA per
// barrier-pair (was 32), staging traffic 2/3 of the 768-K' version.
// ---------------------------------------------------------------------------
__global__ __launch_bounds__(256) void gemm_mfma(
    const u16* __restrict__ xhi, const u16* __restrict__ xlo,
    const u16* __restrict__ BpT,
    const float* __restrict__ bl, const float* __restrict__ br,
    float* __restrict__ xl, float* __restrict__ xr)
{
    __shared__ u16 Ahs[128 * 32];
    __shared__ u16 Als[128 * 32];
    __shared__ u16 Bhs[128 * 32];
    __shared__ u16 Bls[128 * 32];

    // XCD-aware swizzle: 2048 blocks, 8 XCDs -> each XCD owns one N-tile.
    const int raw = blockIdx.x;
    const int swz = (raw & 7) * 256 + (raw >> 3);
    const int mt = swz & 255, nt = swz >> 8;
    const int m0 = mt * 128, n0 = nt * 128;

    const int tid  = threadIdx.x;
    const int lane = tid & 63;
    const int wid  = tid >> 6;
    const int wr   = wid >> 1, wc = wid & 1;      // 64x64 wave tile
    const int lr   = lane & 15;
    const int lk   = lane >> 4;

    f32x4 acc[4][4] = {};

    for (int q = 0; q < 8; ++q) {                 // 32-K slices of K=256
        __syncthreads();
#pragma unroll
        for (int half = 0; half < 2; ++half) {
            const int w   = half * 256 + tid;     // 0..511 within each matrix
            const int row = w >> 2, cc = w & 3;
            const int cs  = cc ^ (row & 3) ^ ((row >> 2) & 3);
            const int ko  = q * 32 + cs * 8;
            gload16(&xhi[(size_t)(m0 + row) * 256 + ko],       &Ahs[w * 8]);
            gload16(&xlo[(size_t)(m0 + row) * 256 + ko],       &Als[w * 8]);
            gload16(&BpT[(size_t)(n0 + row) * 512 + ko],       &Bhs[w * 8]);
            gload16(&BpT[(size_t)(n0 + row) * 512 + 256 + ko], &Bls[w * 8]);
        }
        __syncthreads();                          // drains vmcnt before barrier

        s16x8 ah[4], al[4], bh[4], bl_[4];
#pragma unroll
        for (int i = 0; i < 4; ++i) {
            const int ar  = wr * 64 + i * 16 + lr;
            const int aof = ar * 32 + ((lk ^ (ar & 3) ^ ((ar >> 2) & 3)) << 3);
            ah[i] = *(const s16x8*)&Ahs[aof];
            al[i] = *(const s16x8*)&Als[aof];
            const int brw = wc * 64 + i * 16 + lr;
            const int bof = brw * 32 + ((lk ^ (brw & 3) ^ ((brw >> 2) & 3)) << 3);
            bh[i]  = *(const s16x8*)&Bhs[bof];
            bl_[i] = *(const s16x8*)&Bls[bof];
        }
#pragma unroll
        for (int i = 0; i < 4; ++i)
#pragma unroll
            for (int j = 0; j < 4; ++j) {
                acc[i][j] = __builtin_amdgcn_mfma_f32_16x16x32_bf16(ah[i], bh[j],  acc[i][j], 0, 0, 0);
                acc[i][j] = __builtin_amdgcn_mfma_f32_16x16x32_bf16(ah[i], bl_[j], acc[i][j], 0, 0, 0);
                acc[i][j] = __builtin_amdgcn_mfma_f32_16x16x32_bf16(al[i], bh[j],  acc[i][j], 0, 0, 0);
            }
    }

    // Epilogue: C row = (lane>>4)*4 + r (+16*i), col = lr (+16*j); add bias.
    float* const outp = (n0 < 512) ? xl : xr;
    const int ocol0 = n0 & 511;
    const float* const bb = (n0 < 512) ? bl : br;
#pragma unroll
    for (int j = 0; j < 4; ++j) {
        const int col = ocol0 + wc * 64 + j * 16 + lr;
        const float bv = bb[col];
#pragma unroll
        for (int i = 0; i < 4; ++i) {
#pragma unroll
            for (int r = 0; r < 4; ++r) {
                const int rowg = m0 + wr * 64 + i * 16 + lk * 4 + r;
                outp[(size_t)rowg * 512 + col] = acc[i][j][r] + bv;
            }
        }
    }
}

// ---------------------------------------------------------------------------
// Counting sort of edges by dst
// ---------------------------------------------------------------------------
__global__ void k_hist(const int* __restrict__ ei, int* __restrict__ counts)
{
    int e = blockIdx.x * 256 + threadIdx.x;
    if (e < N_EDGES) atomicAdd(&counts[ei[N_EDGES + e]], 1);
}

__global__ __launch_bounds__(1024) void k_scan(
    const int* __restrict__ counts, int* __restrict__ offsets, int* __restrict__ cursors)
{
    __shared__ int part[1024];
    const int tid = threadIdx.x;
    const int base = tid * 32;
    int loc[32];
    int s = 0;
#pragma unroll
    for (int i = 0; i < 32; ++i) { loc[i] = s; s += counts[base + i]; }
    part[tid] = s;
    __syncthreads();
    const int own = s;
    for (int off = 1; off < 1024; off <<= 1) {
        int v = (tid >= off) ? part[tid - off] : 0;
        __syncthreads();
        part[tid] += v;
        __syncthreads();
    }
    const int pre = part[tid] - own;   // exclusive prefix of chunk
#pragma unroll
    for (int i = 0; i < 32; ++i) {
        int o = pre + loc[i];
        offsets[base + i] = o;
        cursors[base + i] = o;
    }
}

__global__ void k_scatter(const int* __restrict__ ei, int* __restrict__ cursors,
                          int* __restrict__ sorted_src, int* __restrict__ sorted_dst,
                          int* __restrict__ sorted_eid)
{
    int e = blockIdx.x * 256 + threadIdx.x;
    if (e >= N_EDGES) return;
    int d = ei[N_EDGES + e];
    int pos = atomicAdd(&cursors[d], 1);
    sorted_src[pos] = ei[e];
    sorted_dst[pos] = d;
    sorted_eid[pos] = e;
}

// ---------------------------------------------------------------------------
// Prep: eabf[pos][32] bf16 = ea[sorted_eid[pos]][.] gathered into sorted
// order with the same per-row chunk swizzle (row = pos&63) baked in.
// ---------------------------------------------------------------------------
__global__ __launch_bounds__(256) void k_prep_ea(
    const float* __restrict__ ea, const int* __restrict__ sorted_eid,
    u16* __restrict__ eabf)
{
    const int g = blockIdx.x * 256 + threadIdx.x;      // E*32 elements
    const int pos = g >> 5, kk = g & 31;
    const int c = kk >> 3, j = kk & 7;
    const int s = (pos & 3) ^ ((pos >> 2) & 3);
    const int ksrc = ((c ^ s) << 3) + j;
    eabf[g] = f2bf(ea[(size_t)sorted_eid[pos] * 32 + ksrc]);
}

// ---------------------------------------------------------------------------
// k_logit v2: per-edge logits via one 16x16x32 bf16 MFMA per head-quadrant.
// Tile = 64 edges x 128 channels (blockIdx.y = slab -> heads 2s,2s+1).
// Ws (8KB) and Ae (4KB) staged with pure contiguous gload16 from pre-swizzled
// webf/eabf. LDS ~12.8KB -> high occupancy to hide the xl/xr gather latency.
// ---------------------------------------------------------------------------
#define LT_TILES 8

__global__ __launch_bounds__(256, 6) void k_logit(
    const float* __restrict__ xl, const float* __restrict__ xr,
    const u16* __restrict__ eabf, const u16* __restrict__ webf,
    const float* __restrict__ att,
    const int* __restrict__ sorted_src, const int* __restrict__ sorted_dst,
    float* __restrict__ logits)
{
    __shared__ u16 Ws[128 * 32];
    __shared__ u16 Ae[64 * 32];
    __shared__ int src_s[64], dst_s[64];

    const int tid  = threadIdx.x;
    const int lane = tid & 63;
    const int wid  = tid >> 6;
    const int slab = blockIdx.y;                 // 0..3
    const int lr   = lane & 15;
    const int lk   = lane >> 4;

    // Stage Ws: 512 chunks of 16B, linear dest, pre-swizzled source.
#pragma unroll
    for (int p = 0; p < 2; ++p) {
        const int chunk = p * 256 + tid;
        gload16(&webf[(size_t)slab * 4096 + chunk * 8], &Ws[chunk * 8]);
    }
    float attw[8];
#pragma unroll
    for (int f = 0; f < 8; ++f) attw[f] = att[slab * 128 + f * 16 + lr];

    const int sxor = (lr & 3) ^ (lr >> 2);       // row-chunk swizzle (row<64: bits from lr)
    const int swoff = (lk ^ sxor) << 3;

    for (int t = 0; t < LT_TILES; ++t) {
        const int ebase = (blockIdx.x * LT_TILES + t) * 64;
        __syncthreads();                          // Ae/meta safe to overwrite
        if (tid < 64) {
            src_s[tid] = sorted_src[ebase + tid];
            dst_s[tid] = sorted_dst[ebase + tid];
        }
        gload16(&eabf[(size_t)ebase * 32 + tid * 8], &Ae[tid * 8]);
        __syncthreads();                          // drains vmcnt + lgkm

        // One MFMA per head-quadrant f (K=32).
        const s16x8 afr = *(const s16x8*)&Ae[(wid * 16 + lr) * 32 + swoff];
        f32x4 acc[8];
#pragma unroll
        for (int f = 0; f < 8; ++f) {
            const s16x8 bfr = *(const s16x8*)&Ws[(f * 16 + lr) * 32 + swoff];
            acc[f] = __builtin_amdgcn_mfma_f32_16x16x32_bf16(
                afr, bfr, (f32x4){0.f, 0.f, 0.f, 0.f}, 0, 0, 0);
        }

        // Epilogue: z = acc + xl[src] + xr[dst]; lrelu; att-weighted sums.
        float p0[4], p1[4];
#pragma unroll
        for (int r = 0; r < 4; ++r) { p0[r] = 0.f; p1[r] = 0.f; }
#pragma unroll
        for (int r = 0; r < 4; ++r) {
            const int el = wid * 16 + lk * 4 + r;           // local edge 0..63
            const size_t sb = (size_t)src_s[el] * 512 + slab * 128 + lr;
            const size_t db = (size_t)dst_s[el] * 512 + slab * 128 + lr;
#pragma unroll
            for (int f = 0; f < 8; ++f) {
                const float z = acc[f][r] + xl[sb + f * 16] + xr[db + f * 16];
                const float tt = z > 0.f ? z : NEG * z;
                if (f < 4) p0[r] += attw[f] * tt;
                else       p1[r] += attw[f] * tt;
            }
        }
#pragma unroll
        for (int o = 1; o < 16; o <<= 1) {
#pragma unroll
            for (int r = 0; r < 4; ++r) {
                p0[r] += __shfl_xor(p0[r], o);
                p1[r] += __shfl_xor(p1[r], o);
            }
        }
        if (lr == 0) {
#pragma unroll
            for (int r = 0; r < 4; ++r) {
                const size_t eg = ebase + wid * 16 + lk * 4 + r;
                logits[eg * 8 + slab * 2]     = p0[r];
                logits[eg * 8 + slab * 2 + 1] = p1[r];
            }
        }
    }
}

// ---------------------------------------------------------------------------
// k_agg: per-dst two-pass softmax + weighted xl[src] gather-sum, h, score.
// ---------------------------------------------------------------------------
#define AGG_DPB 8

__global__ __launch_bounds__(256, 8) void k_agg(
    const float* __restrict__ xl, const float* __restrict__ logits,
    const int* __restrict__ sorted_src,
    const int* __restrict__ offsets, const int* __restrict__ counts,
    const float* __restrict__ bias, const float* __restrict__ pw,
    float* __restrict__ h, float* __restrict__ score)
{
    __shared__ float red_s[4];

    const int tid = threadIdx.x;
    const int wv  = tid >> 6;
    const int l   = tid & 63;
    const int c0  = tid * 2;
    const int head = tid >> 5;

    const float2 bv  = *(const float2*)&bias[c0];
    const float2 pwv = *(const float2*)&pw[c0];

    float nrm = pwv.x * pwv.x + pwv.y * pwv.y;
#pragma unroll
    for (int o = 1; o < 64; o <<= 1) nrm += __shfl_xor(nrm, o);
    if (l == 0) red_s[wv] = nrm;
    __syncthreads();
    const float inv_nrm = 1.0f / sqrtf(red_s[0] + red_s[1] + red_s[2] + red_s[3]);

    for (int dd = 0; dd < AGG_DPB; ++dd) {
        const int d   = blockIdx.x * AGG_DPB + dd;
        const int off = offsets[d];
        const int deg = counts[d];

        float m = -INFINITY;
        for (int j = 0; j < deg; ++j)
            m = fmaxf(m, logits[(size_t)(off + j) * 8 + head]);

        float den = 0.f, a0 = 0.f, a1 = 0.f;
        for (int j = 0; j < deg; ++j) {
            const float lg = logits[(size_t)(off + j) * 8 + head];
            const int   s  = sorted_src[off + j];
            const float2 xl2 = *(const float2*)&xl[(size_t)s * 512 + c0];
            const float pe = __expf(lg - m);
            den += pe;
            a0 += pe * xl2.x;
            a1 += pe * xl2.y;
        }

        const float r = den > 0.f ? 1.0f / den : 0.f;
        const float h0 = fmaxf(a0 * r + bv.x, 0.f);
        const float h1 = fmaxf(a1 * r + bv.y, 0.f);
        *(float2*)&h[(size_t)d * 512 + c0] = make_float2(h0, h1);

        float ps = h0 * pwv.x + h1 * pwv.y;
#pragma unroll
        for (int o = 1; o < 64; o <<= 1) ps += __shfl_xor(ps, o);
        __syncthreads();
        if (l == 0) red_s[wv] = ps;
        __syncthreads();
        if (tid == 0)
            score[d] = tanhf((red_s[0] + red_s[1] + red_s[2] + red_s[3]) * inv_nrm);
    }
}

// ---------------------------------------------------------------------------
// Per-graph top-K via bitonic sort of packed keys (score desc, idx asc)
// ---------------------------------------------------------------------------
__global__ __launch_bounds__(256) void k_topk(const float* __restrict__ score,
                                              int* __restrict__ sel_idx,
                                              float* __restrict__ sel_val)
{
    __shared__ unsigned long long key[1024];
    const int g = blockIdx.x, tid = threadIdx.x;
    for (int i = tid; i < 1024; i += 256) {
        float s = score[g * 1024 + i];
        unsigned u = __float_as_uint(s);
        u = (u & 0x80000000u) ? ~u : (u | 0x80000000u);   // orderable, ascending
        key[i] = ((unsigned long long)(~u) << 32) | (unsigned)i;  // asc key == desc score
    }
    __syncthreads();
    for (int k = 2; k <= 1024; k <<= 1) {
        for (int j = k >> 1; j > 0; j >>= 1) {
            for (int i = tid; i < 1024; i += 256) {
                int ixj = i ^ j;
                if (ixj > i) {
                    bool up = ((i & k) == 0);
                    unsigned long long a = key[i], b = key[ixj];
                    if ((a > b) == up) { key[i] = b; key[ixj] = a; }
                }
            }
            __syncthreads();
        }
    }
    for (int kk = tid; kk < KSEL; kk += 256) {
        int idx = (int)(key[kk] & 0xFFFFFFFFu);
        sel_idx[g * KSEL + kk] = idx;
        sel_val[g * KSEL + kk] = score[g * 1024 + idx];
    }
}

// ---------------------------------------------------------------------------
// Pool: gmp = max_k(h[idx_k]*val_k), gap = mean_k(...) — k-sliced + merge
// ---------------------------------------------------------------------------
#define KSLICE 103

__global__ __launch_bounds__(256) void k_pool_part(
    const float* __restrict__ h, const int* __restrict__ sel_idx,
    const float* __restrict__ sel_val, float* __restrict__ part)
{
    const int g = blockIdx.x >> 3, sl = blockIdx.x & 7;
    const int kbeg = sl * KSLICE;
    const int kend = min(KSEL, kbeg + KSLICE);
    const int n = kend - kbeg;
    __shared__ float vs[KSLICE];
    __shared__ int   is_[KSLICE];
    const int tid = threadIdx.x;
    if (tid < n) {
        vs[tid]  = sel_val[g * KSEL + kbeg + tid];
        is_[tid] = sel_idx[g * KSEL + kbeg + tid];
    }
    __syncthreads();
    const int c0 = tid, c1 = tid + 256;
    float mx0 = -INFINITY, mx1 = -INFINITY, s0 = 0.f, s1 = 0.f;
    for (int kk = 0; kk < n; ++kk) {
        const float* hp = h + ((size_t)(g * 1024 + is_[kk])) * 512;
        const float v = vs[kk];
        float f0 = hp[c0] * v, f1 = hp[c1] * v;
        mx0 = fmaxf(mx0, f0); s0 += f0;
        mx1 = fmaxf(mx1, f1); s1 += f1;
    }
    const size_t base = ((size_t)blockIdx.x * 2) * 512;
    part[base + c0] = mx0;        part[base + c1] = mx1;
    part[base + 512 + c0] = s0;   part[base + 512 + c1] = s1;
}

__global__ __launch_bounds__(256) void k_pool_merge(
    const float* __restrict__ part, float* __restrict__ out)
{
    const int g = blockIdx.x, tid = threadIdx.x;
    const int c0 = tid, c1 = tid + 256;
    float mx0 = -INFINITY, mx1 = -INFINITY, s0 = 0.f, s1 = 0.f;
    for (int sl = 0; sl < 8; ++sl) {
        const size_t base = ((size_t)(g * 8 + sl) * 2) * 512;
        mx0 = fmaxf(mx0, part[base + c0]); mx1 = fmaxf(mx1, part[base + c1]);
        s0 += part[base + 512 + c0];       s1 += part[base + 512 + c1];
    }
    out[(size_t)g * 1024 + c0] = mx0;
    out[(size_t)g * 1024 + c1] = mx1;
    out[(size_t)g * 1024 + 512 + c0] = s0 * (1.f / KSEL);
    out[(size_t)g * 1024 + 512 + c1] = s1 * (1.f / KSEL);
}

// ---------------------------------------------------------------------------
extern "C" void kernel_launch(void* const* d_in, const int* in_sizes, int n_in,
                              void* d_out, int out_size, void* d_ws, size_t ws_size,
                              hipStream_t stream)
{
    const float* x    = (const float*)d_in[0];
    const float* ea   = (const float*)d_in[1];
    const float* Wl   = (const float*)d_in[2];
    const float* bl   = (const float*)d_in[3];
    const float* Wr   = (const float*)d_in[4];
    const float* br   = (const float*)d_in[5];
    const float* We   = (const float*)d_in[6];
    const float* att  = (const float*)d_in[7];
    const float* bias = (const float*)d_in[8];
    const float* pw   = (const float*)d_in[9];
    const int*   ei   = (const int*)d_in[10];
    float* out = (float*)d_out;

    // workspace layout (4B units unless noted)
    float* xl        = (float*)d_ws;                      // N*512
    float* xr        = xl + (size_t)N_NODES * 512;
    float* h         = xr + (size_t)N_NODES * 512;
    float* logits    = h + (size_t)N_NODES * 512;         // E*8
    float* sel_val   = logits + (size_t)N_EDGES * 8;      // 32*820
    float* part      = sel_val + BGRAPH * KSEL;           // 256*2*512
    float* score     = part + 256 * 2 * 512;              // 32768
    int* counts      = (int*)(score + N_NODES);
    int* offsets     = counts + N_NODES;
    int* cursors     = offsets + N_NODES;
    int* sorted_src  = cursors + N_NODES;                 // E
    int* sorted_dst  = sorted_src + N_EDGES;              // E
    int* sorted_eid  = sorted_dst + N_EDGES;              // E
    int* sel_idx     = sorted_eid + N_EDGES;              // 32*820
    u16* xhi         = (u16*)(sel_idx + BGRAPH * KSEL);   // N*256 u16
    u16* xlo         = xhi + (size_t)N_NODES * 256;       // N*256 u16
    u16* bpt         = xlo + (size_t)N_NODES * 256;       // 1024*512 u16
    u16* webf        = bpt + (size_t)1024 * 512;          // 4*128*32 u16
    u16* eabf        = webf + 4 * 128 * 32;               // E*32 u16

    hipMemsetAsync(counts, 0, (size_t)N_NODES * sizeof(int), stream);

    k_split_x<<<(N_NODES * 256) / (4 * 256), 256, 0, stream>>>(x, xhi, xlo);
    k_pack_bt<<<dim3(2, 1024), 256, 0, stream>>>(Wl, Wr, bpt);
    k_prep_we<<<64, 256, 0, stream>>>(We, webf);
    gemm_mfma<<<2048, 256, 0, stream>>>(xhi, xlo, bpt, bl, br, xl, xr);

    k_hist<<<N_EDGES / 256, 256, 0, stream>>>(ei, counts);
    k_scan<<<1, 1024, 0, stream>>>(counts, offsets, cursors);
    k_scatter<<<N_EDGES / 256, 256, 0, stream>>>(ei, cursors, sorted_src, sorted_dst, sorted_eid);
    k_prep_ea<<<(N_EDGES * 32) / 256, 256, 0, stream>>>(ea, sorted_eid, eabf);
    k_logit<<<dim3(N_EDGES / 64 / LT_TILES, 4), 256, 0, stream>>>(
        xl, xr, eabf, webf, att, sorted_src, sorted_dst, logits);
    k_agg<<<N_NODES / AGG_DPB, 256, 0, stream>>>(xl, logits, sorted_src, offsets, counts,
                                                 bias, pw, h, score);
    k_topk<<<BGRAPH, 256, 0, stream>>>(score, sel_idx, sel_val);
    k_pool_part<<<BGRAPH * 8, 256, 0, stream>>>(h, sel_idx, sel_val, part);
    k_pool_merge<<<BGRAPH, 256, 0, stream>>>(part, out);
}